// Round 6
// baseline (804.124 us; speedup 1.0000x reference)
//
#include <hip/hip_runtime.h>
#include <cmath>

#define TW 32
#define RCH 64           // output rows per chunk
#define NCH 8            // chunks per 512-row stripe
#define BUF 74           // circular h-result buffer rows (RCH + 10)
#define IMG 512
#define SSIM_C1 1e-4f
#define SSIM_C2 9e-4f

struct GaussWin { float g[11]; };

typedef float v2f __attribute__((ext_vector_type(2)));

__device__ __forceinline__ v2f pk_fma(v2f a, v2f b, v2f c) {
    return __builtin_elementwise_fma(a, b, c);
}

// Bank-decorrelating column swizzle (round-3 verified: odd row multiplier).
__device__ __forceinline__ int swz(int col, int row) {
    return (col & 24) | ((col + 2 * (col >> 3) + 5 * row) & 7);
}

// Persistent-stripe kernel: each block owns a 32-col x 512-row stripe of one
// plane. 8 chunks of 64 rows stream through a 74-row circular LDS buffer of
// h-pass results; each image row is h-passed exactly once (vs 1.21x for the
// round-5 tiled version), and the grid (768 blocks = 3/CU) is exactly
// co-resident -- no launch tail.
__launch_bounds__(256, 3)
__global__ void ssim_stripe_kernel(const float* __restrict__ x,
                                   const float* __restrict__ y,
                                   const float* __restrict__ conf,
                                   float* __restrict__ partials,
                                   float* __restrict__ out,
                                   int use_ws, float scale,
                                   GaussWin W) {
    __shared__ float4 s_h4[BUF * TW];   // 37888 B  (mu_x, mu_y, sxx, syy)
    __shared__ float  s_h1[BUF * TW];   //  9472 B  (sxy)
    __shared__ float  s_red[4];         // 47.4 KB total -> 3 blocks/CU

    const int tid = threadIdx.x;
    const int plane = blockIdx.y;              // b*3 + c, 48 planes
    const int tx0 = blockIdx.x * TW;
    const int pbase = plane * (IMG * IMG);
    const int cbase = (plane / 3) * (IMG * IMG);

    // Gaussian symmetric: g[k] == g[10-k] bitwise. 6 distinct packed weights.
    constexpr int WI[11] = {0,1,2,3,4,5,4,3,2,1,0};
    v2f w2[6];
    #pragma unroll
    for (int i = 0; i < 6; i++) w2[i] = (v2f){W.g[i], W.g[i]};

    const bool xint = (blockIdx.x >= 1) & (blockIdx.x <= 14);

    const int c   = tid & 31;            // phase-2 column
    const int grp = tid >> 5;            // phase-2 row group (8 groups x 8 rows)

    float lsum = 0.f;

    for (int chunk = 0; chunk < NCH; ++chunk) {
        // ---- Phase 1: h-pass new rows into the circular buffer ----
        // chunk 0: h-rows [-5, 69) (74 rows, 296 strip-tasks -> 2 rounds);
        // chunk t>0: h-rows [64t+5, 64t+69) (64 rows, exactly 256 tasks).
        const int rbase = (chunk == 0) ? -5 : chunk * RCH + 5;
        const int ntask = ((chunk == 0) ? BUF : RCH) * 4;
        // Rows are guaranteed in-image except in the first/last chunk.
        const bool fast = xint & (chunk != 0) & (chunk != NCH - 1);

        for (int task = tid; task < ntask; task += 256) {
            const int r  = task >> 2;
            const int cs = (task & 3) * 8;           // output cols cs..cs+7
            const int gy = rbase + r;
            const int slot = (gy + 5) % BUF;         // physical buffer row
            const float* xrow = x + pbase + gy * IMG;
            const float* yrow = y + pbase + gy * IMG;
            const int c0 = tx0 + cs - 6;             // 20-float window base

            // Load cols [c0, c0+20): pieces x2,x4,x4,x4,x4,x2 (c0 == 2 mod 8,
            // so every piece is aligned and never straddles 0/512 -> exact
            // zero padding).
            float vxa[20], vya[20];
            if (fast) {
                float2 p0x = *(const float2*)(xrow + c0);
                float4 p1x = *(const float4*)(xrow + c0 + 2);
                float4 p2x = *(const float4*)(xrow + c0 + 6);
                float4 p3x = *(const float4*)(xrow + c0 + 10);
                float4 p4x = *(const float4*)(xrow + c0 + 14);
                float2 p5x = *(const float2*)(xrow + c0 + 18);
                float2 p0y = *(const float2*)(yrow + c0);
                float4 p1y = *(const float4*)(yrow + c0 + 2);
                float4 p2y = *(const float4*)(yrow + c0 + 6);
                float4 p3y = *(const float4*)(yrow + c0 + 10);
                float4 p4y = *(const float4*)(yrow + c0 + 14);
                float2 p5y = *(const float2*)(yrow + c0 + 18);
                vxa[0]=p0x.x; vxa[1]=p0x.y;
                vxa[2]=p1x.x; vxa[3]=p1x.y; vxa[4]=p1x.z; vxa[5]=p1x.w;
                vxa[6]=p2x.x; vxa[7]=p2x.y; vxa[8]=p2x.z; vxa[9]=p2x.w;
                vxa[10]=p3x.x; vxa[11]=p3x.y; vxa[12]=p3x.z; vxa[13]=p3x.w;
                vxa[14]=p4x.x; vxa[15]=p4x.y; vxa[16]=p4x.z; vxa[17]=p4x.w;
                vxa[18]=p5x.x; vxa[19]=p5x.y;
                vya[0]=p0y.x; vya[1]=p0y.y;
                vya[2]=p1y.x; vya[3]=p1y.y; vya[4]=p1y.z; vya[5]=p1y.w;
                vya[6]=p2y.x; vya[7]=p2y.y; vya[8]=p2y.z; vya[9]=p2y.w;
                vya[10]=p3y.x; vya[11]=p3y.y; vya[12]=p3y.z; vya[13]=p3y.w;
                vya[14]=p4y.x; vya[15]=p4y.y; vya[16]=p4y.z; vya[17]=p4y.w;
                vya[18]=p5y.x; vya[19]=p5y.y;
            } else {
                const bool rowok = ((unsigned)gy < IMG);
                #pragma unroll
                for (int i = 0; i < 20; i++) { vxa[i] = 0.f; vya[i] = 0.f; }
                {   int cc = c0;
                    if (rowok && cc >= 0 && cc + 2 <= IMG) {
                        float2 a = *(const float2*)(xrow + cc);
                        float2 b = *(const float2*)(yrow + cc);
                        vxa[0]=a.x; vxa[1]=a.y; vya[0]=b.x; vya[1]=b.y;
                    } }
                #pragma unroll
                for (int q = 0; q < 4; q++) {
                    int cc = c0 + 2 + 4 * q;
                    if (rowok && cc >= 0 && cc + 4 <= IMG) {
                        float4 a = *(const float4*)(xrow + cc);
                        float4 b = *(const float4*)(yrow + cc);
                        vxa[2+4*q]=a.x; vxa[3+4*q]=a.y; vxa[4+4*q]=a.z; vxa[5+4*q]=a.w;
                        vya[2+4*q]=b.x; vya[3+4*q]=b.y; vya[4+4*q]=b.z; vya[5+4*q]=b.w;
                    } }
                {   int cc = c0 + 18;
                    if (rowok && cc >= 0 && cc + 2 <= IMG) {
                        float2 a = *(const float2*)(xrow + cc);
                        float2 b = *(const float2*)(yrow + cc);
                        vxa[18]=a.x; vxa[19]=a.y; vya[18]=b.x; vya[19]=b.y;
                    } }
            }

            // Streaming tap-major conv: output j uses window element w=k-j
            // for k in [j, j+10]; image col of tap k is vxa[k+1].
            v2f amu[8], as2[8];
            float axy[8];
            #pragma unroll
            for (int j = 0; j < 8; j++) { amu[j]=(v2f){0.f,0.f}; as2[j]=(v2f){0.f,0.f}; axy[j]=0.f; }
            #pragma unroll
            for (int k = 0; k < 18; k++) {
                float xv = vxa[k + 1], yv = vya[k + 1];
                v2f xy = (v2f){xv, yv};
                v2f p2 = xy * xy;             // (x^2, y^2) -> v_pk_mul_f32
                float pxy = xv * yv;
                const int jlo = (k - 10 > 0) ? (k - 10) : 0;
                const int jhi = (k < 7) ? k : 7;
                #pragma unroll
                for (int j = jlo; j <= jhi; j++) {
                    v2f w = w2[WI[k - j]];
                    amu[j] = pk_fma(xy, w, amu[j]);
                    as2[j] = pk_fma(p2, w, as2[j]);
                    axy[j] = fmaf(pxy, w.x, axy[j]);
                }
            }
            const int quad = cs & 24;
            const int base0 = cs + 2 * (cs >> 3) + 5 * slot;
            #pragma unroll
            for (int j = 0; j < 8; j++) {
                int pc = quad | ((base0 + j) & 7);
                s_h4[slot * TW + pc] = make_float4(amu[j].x, amu[j].y, as2[j].x, as2[j].y);
                s_h1[slot * TW + pc] = axy[j];
            }
        }

        // Prefetch conf for this chunk's outputs (all rows in-image: 512=8*64).
        const int out_r0 = chunk * RCH + grp * 8;
        float cf[8];
        #pragma unroll
        for (int j = 0; j < 8; j++)
            cf[j] = conf[cbase + (out_r0 + j) * IMG + tx0 + c];

        __syncthreads();   // h-results visible

        // ---- Phase 2: vertical pass, 8 rows per thread ----
        // Needs h-rows out_r0-5 .. out_r0+12 -> starting slot = out_r0 % BUF.
        v2f amu[8], as2[8];
        float axy[8];
        #pragma unroll
        for (int j = 0; j < 8; j++) { amu[j]=(v2f){0.f,0.f}; as2[j]=(v2f){0.f,0.f}; axy[j]=0.f; }

        int slot = out_r0 % BUF;
        const int cquad = c & 24;
        const int cb0 = c + 2 * (c >> 3);
        #pragma unroll
        for (int t = 0; t < 18; t++) {
            int pc = cquad | ((cb0 + 5 * slot) & 7);
            float4 h4 = s_h4[slot * TW + pc];
            float  h1 = s_h1[slot * TW + pc];
            slot = (slot + 1 == BUF) ? 0 : slot + 1;
            v2f hmu = (v2f){h4.x, h4.y};
            v2f hs2 = (v2f){h4.z, h4.w};
            #pragma unroll
            for (int j = 0; j < 8; j++) {
                int k = t - j;                 // constant post-unroll
                if (k >= 0 && k <= 10) {
                    v2f w = w2[WI[k]];
                    amu[j] = pk_fma(hmu, w, amu[j]);
                    as2[j] = pk_fma(hs2, w, as2[j]);
                    axy[j] = fmaf(h1, w.x, axy[j]);
                }
            }
        }

        // ---- Epilogue: SSIM + conf weighting ----
        #pragma unroll
        for (int j = 0; j < 8; j++) {
            float mu_x = amu[j].x, mu_y = amu[j].y;
            float mu_x2 = mu_x * mu_x;
            float mu_y2 = mu_y * mu_y;
            float mu_xy = mu_x * mu_y;
            float sigx  = as2[j].x - mu_x2;
            float sigy  = as2[j].y - mu_y2;
            float sigxy = axy[j] - mu_xy;
            float num = (2.f * mu_xy + SSIM_C1) * (2.f * sigxy + SSIM_C2);
            float den = (mu_x2 + mu_y2 + SSIM_C1) * (sigx + sigy + SSIM_C2);
            float ssim = num * __builtin_amdgcn_rcpf(den);   // den >= C1*C2 > 0
            float loss = 1.f - ssim;
            loss = fminf(fmaxf(loss, 0.f), 1.f);
            lsum = fmaf(loss, cf[j], lsum);
        }

        __syncthreads();   // all reads done before next chunk overwrites slots
    }

    // ---- Block reduction ----
    #pragma unroll
    for (int off = 32; off; off >>= 1) lsum += __shfl_down(lsum, off, 64);
    if ((tid & 63) == 0) s_red[tid >> 6] = lsum;
    __syncthreads();
    if (tid == 0) {
        float t = s_red[0] + s_red[1] + s_red[2] + s_red[3];
        if (use_ws) {
            partials[blockIdx.x + gridDim.x * blockIdx.y] = t;
        } else {
            atomicAdd(out, t * scale);
        }
    }
}

// Single-block reduce: writes out[0] directly (no memset, no atomics).
__global__ void reduce_kernel(const float* __restrict__ partials, int n,
                              float* __restrict__ out, float scale) {
    __shared__ float s_red[16];
    float s = 0.f;
    for (int i = threadIdx.x; i < n; i += 1024) s += partials[i];
    #pragma unroll
    for (int off = 32; off; off >>= 1) s += __shfl_down(s, off, 64);
    if ((threadIdx.x & 63) == 0) s_red[threadIdx.x >> 6] = s;
    __syncthreads();
    if (threadIdx.x == 0) {
        float t = 0.f;
        #pragma unroll
        for (int i = 0; i < 16; i++) t += s_red[i];
        out[0] = t * scale;
    }
}

extern "C" void kernel_launch(void* const* d_in, const int* in_sizes, int n_in,
                              void* d_out, int out_size, void* d_ws, size_t ws_size,
                              hipStream_t stream) {
    const float* x    = (const float*)d_in[0];
    const float* y    = (const float*)d_in[1];
    const float* conf = (const float*)d_in[2];
    float* out = (float*)d_out;
    float* partials = (float*)d_ws;

    // Gaussian window, computed like the reference: float64 exp + normalize, cast f32
    GaussWin W;
    {
        double gd[11], s = 0.0;
        for (int i = 0; i < 11; i++) { gd[i] = exp(-((i - 5) * (i - 5)) / 4.5); s += gd[i]; }
        for (int i = 0; i < 11; i++) W.g[i] = (float)(gd[i] / s);
    }

    const int B = 16, C = 3;
    const float scale = 1.0f / (float)(B * C * IMG * IMG);
    dim3 grid(IMG / TW, B * C);                 // 16 x 48 = 768 blocks = 3/CU
    const int nblocks = (IMG / TW) * B * C;
    const int use_ws = (ws_size >= (size_t)nblocks * sizeof(float)) ? 1 : 0;

    if (!use_ws) {
        // fallback: atomic accumulation into d_out (poisoned before each call)
        hipMemsetAsync(d_out, 0, sizeof(float), stream);
    }
    ssim_stripe_kernel<<<grid, 256, 0, stream>>>(x, y, conf, partials, out, use_ws, scale, W);
    if (use_ws) {
        reduce_kernel<<<1, 1024, 0, stream>>>(partials, nblocks, out, scale);
    }
}

// Round 7
// 164.663 us; speedup vs baseline: 4.8834x; 4.8834x over previous
//
#include <hip/hip_runtime.h>
#include <cmath>

#define TW 32
#define TH 48
#define HR (TH + 10)     // 58 rows of h-pass results
#define LSTRIDE 33       // padded LDS row stride (float4 / float units)
#define IMG 512
#define SSIM_C1 1e-4f
#define SSIM_C2 9e-4f

struct GaussWin { float g[11]; };

typedef float v2f __attribute__((ext_vector_type(2)));

// Native packed fp32 -> v_pk_fma_f32 / v_pk_mul_f32 (gfx90a+ HasPackedFP32Ops).
__device__ __forceinline__ v2f pk_fma(v2f a, v2f b, v2f c) {
    return __builtin_elementwise_fma(a, b, c);
}

// LDS layout: stride-33 padding instead of the round-5 index swizzle.
//  - phase-2 b128 reads: 8-lane groups hit banks 4(r+c)+{0..3} -> full 32-bank
//    span, conflict-free; s_h1 b32 reads: (r+c)%32 permutation, conflict-free.
//  - phase-1 writes: 4-way conflicted (cs in {0,8,16,24} aliases mod 8) --
//    ~1-2 us total, accepted to make EVERY LDS address a compile-time
//    immediate (ds_*_b128 offset:528*t etc.), deleting ~190 VALU/thread of
//    swizzle arithmetic.
__launch_bounds__(256, 4)
__global__ void ssim_tile_kernel(const float* __restrict__ x,
                                 const float* __restrict__ y,
                                 const float* __restrict__ conf,
                                 float* __restrict__ partials,
                                 float* __restrict__ out,
                                 int use_ws, float scale,
                                 GaussWin W) {
    __shared__ float4 s_h4[HR * LSTRIDE];   // 30624 B  (mu_x, mu_y, sxx, syy)
    __shared__ float  s_h1[HR * LSTRIDE];   //  7656 B  (sxy)
    __shared__ float  s_red[4];             // 38.3 KB total -> 4 blocks/CU

    const int tid = threadIdx.x;
    const int plane = blockIdx.z;              // b*3 + c
    const int tx0 = blockIdx.x * TW;
    const int ty0 = blockIdx.y * TH;
    const int pbase = plane * (IMG * IMG);
    const int cbase = (plane / 3) * (IMG * IMG);

    // Gaussian symmetric: g[k] == g[10-k] bitwise. 6 distinct packed weights.
    constexpr int WI[11] = {0,1,2,3,4,5,4,3,2,1,0};
    v2f w2[6];
    #pragma unroll
    for (int i = 0; i < 6; i++) w2[i] = (v2f){W.g[i], W.g[i]};

    // Interior blocks touch no image border anywhere in the halo window.
    const bool interior = (blockIdx.x >= 1) & (blockIdx.x <= 14) &
                          (blockIdx.y >= 1) & (blockIdx.y <= 9);

    // ---- Phase 1: horizontal pass, direct from global ----
    // 58 rows x 4 col-groups = 232 strips, one per thread, one round.
    // Strip = 8 output cols; reads 6 aligned float4s per array covering cols
    // [cs-8, cs+16); elements 3..20 are the 18 taps. 16B-aligned reads are
    // fully in- or out-of-bounds -> exact zero padding.
    if (tid < HR * 4) {
        const int r = tid >> 2;
        const int cs = (tid & 3) * 8;
        const int gy = ty0 - 5 + r;
        const float* xrow = x + pbase + gy * IMG;
        const float* yrow = y + pbase + gy * IMG;
        const int c0 = tx0 + cs - 8;

        float4 fx[6], fy[6];
        if (interior) {
            #pragma unroll
            for (int q = 0; q < 6; q++) {
                fx[q] = *(const float4*)(xrow + c0 + 4 * q);
                fy[q] = *(const float4*)(yrow + c0 + 4 * q);
            }
        } else {
            const bool rowok = ((unsigned)gy < IMG);
            #pragma unroll
            for (int q = 0; q < 6; q++) {
                int col = c0 + 4 * q;
                fx[q] = make_float4(0.f, 0.f, 0.f, 0.f);
                fy[q] = make_float4(0.f, 0.f, 0.f, 0.f);
                if (rowok && (unsigned)col <= (unsigned)(IMG - 4)) {
                    fx[q] = *(const float4*)(xrow + col);
                    fy[q] = *(const float4*)(yrow + col);
                }
            }
        }
        float vxa[24], vya[24];
        #pragma unroll
        for (int q = 0; q < 6; q++) {
            vxa[4*q+0]=fx[q].x; vxa[4*q+1]=fx[q].y; vxa[4*q+2]=fx[q].z; vxa[4*q+3]=fx[q].w;
            vya[4*q+0]=fy[q].x; vya[4*q+1]=fy[q].y; vya[4*q+2]=fy[q].z; vya[4*q+3]=fy[q].w;
        }

        // Streaming tap-major conv.
        v2f amu[8], as2[8];
        float axy[8];
        #pragma unroll
        for (int j = 0; j < 8; j++) { amu[j]=(v2f){0.f,0.f}; as2[j]=(v2f){0.f,0.f}; axy[j]=0.f; }
        #pragma unroll
        for (int k = 0; k < 18; k++) {
            float xv = vxa[k + 3], yv = vya[k + 3];
            v2f xy = (v2f){xv, yv};
            v2f p2 = xy * xy;                 // (x^2, y^2) -> v_pk_mul_f32
            float pxy = xv * yv;
            const int jlo = (k - 10 > 0) ? (k - 10) : 0;
            const int jhi = (k < 7) ? k : 7;
            #pragma unroll
            for (int j = jlo; j <= jhi; j++) {
                v2f w = w2[WI[k - j]];
                amu[j] = pk_fma(xy, w, amu[j]);
                as2[j] = pk_fma(p2, w, as2[j]);
                axy[j] = fmaf(pxy, w.x, axy[j]);
            }
        }
        float4* h4p = &s_h4[r * LSTRIDE + cs];
        float*  h1p = &s_h1[r * LSTRIDE + cs];
        #pragma unroll
        for (int j = 0; j < 8; j++) {
            h4p[j] = make_float4(amu[j].x, amu[j].y, as2[j].x, as2[j].y);
            h1p[j] = axy[j];
        }
    }

    // Prefetch conf (consumed in epilogue) before the barrier.
    const int c  = tid & 31;
    const int r0 = (tid >> 5) * 6;            // 8 groups x 6 rows = 48 rows
    float cf[6];
    #pragma unroll
    for (int j = 0; j < 6; j++) {
        int gy = ty0 + r0 + j;
        cf[j] = (gy < IMG) ? conf[cbase + gy * IMG + tx0 + c] : 0.f;
    }
    __syncthreads();

    // ---- Phase 2: vertical pass, 6 vertically-adjacent outputs per thread ----
    v2f amu[6], as2[6];
    float axy[6];
    #pragma unroll
    for (int j = 0; j < 6; j++) { amu[j]=(v2f){0.f,0.f}; as2[j]=(v2f){0.f,0.f}; axy[j]=0.f; }

    const float4* h4p = &s_h4[r0 * LSTRIDE + c];
    const float*  h1p = &s_h1[r0 * LSTRIDE + c];
    #pragma unroll
    for (int t = 0; t < 16; t++) {
        float4 h4 = h4p[t * LSTRIDE];         // imm offset 528*t
        float  h1 = h1p[t * LSTRIDE];         // imm offset 132*t
        v2f hmu = (v2f){h4.x, h4.y};
        v2f hs2 = (v2f){h4.z, h4.w};
        #pragma unroll
        for (int j = 0; j < 6; j++) {
            int k = t - j;                    // constant post-unroll
            if (k >= 0 && k <= 10) {
                v2f w = w2[WI[k]];
                amu[j] = pk_fma(hmu, w, amu[j]);
                as2[j] = pk_fma(hs2, w, as2[j]);
                axy[j] = fmaf(h1, w.x, axy[j]);
            }
        }
    }

    // ---- Epilogue: SSIM + conf weighting + accumulate ----
    // Out-of-image rows (by==10 tail) have cf==0 and finite loss (den>0),
    // so they contribute exactly 0 -- no branch needed.
    float lsum = 0.f;
    #pragma unroll
    for (int j = 0; j < 6; j++) {
        float mu_x = amu[j].x, mu_y = amu[j].y;
        float mu_x2 = mu_x * mu_x;
        float mu_y2 = mu_y * mu_y;
        float mu_xy = mu_x * mu_y;
        float sigx  = as2[j].x - mu_x2;
        float sigy  = as2[j].y - mu_y2;
        float sigxy = axy[j] - mu_xy;
        float num = (2.f * mu_xy + SSIM_C1) * (2.f * sigxy + SSIM_C2);
        float den = (mu_x2 + mu_y2 + SSIM_C1) * (sigx + sigy + SSIM_C2);
        float ssim = num * __builtin_amdgcn_rcpf(den);   // den >= C1*C2 > 0
        float loss = 1.f - ssim;
        loss = fminf(fmaxf(loss, 0.f), 1.f);
        lsum = fmaf(loss, cf[j], lsum);
    }

    // ---- Block reduction ----
    #pragma unroll
    for (int off = 32; off; off >>= 1) lsum += __shfl_down(lsum, off, 64);
    if ((tid & 63) == 0) s_red[tid >> 6] = lsum;
    __syncthreads();
    if (tid == 0) {
        float t = s_red[0] + s_red[1] + s_red[2] + s_red[3];
        if (use_ws) {
            partials[blockIdx.x + gridDim.x * (blockIdx.y + gridDim.y * blockIdx.z)] = t;
        } else {
            atomicAdd(out, t * scale);
        }
    }
}

// Single-block reduce: writes out[0] directly (no memset, no atomics).
__global__ void reduce_kernel(const float* __restrict__ partials, int n,
                              float* __restrict__ out, float scale) {
    __shared__ float s_red[16];
    float s = 0.f;
    const float4* p4 = (const float4*)partials;
    const int n4 = n >> 2;
    for (int i = threadIdx.x; i < n4; i += 1024) {
        float4 v = p4[i];
        s += (v.x + v.y) + (v.z + v.w);
    }
    for (int i = (n4 << 2) + threadIdx.x; i < n; i += 1024) s += partials[i];
    #pragma unroll
    for (int off = 32; off; off >>= 1) s += __shfl_down(s, off, 64);
    if ((threadIdx.x & 63) == 0) s_red[threadIdx.x >> 6] = s;
    __syncthreads();
    if (threadIdx.x == 0) {
        float t = 0.f;
        #pragma unroll
        for (int i = 0; i < 16; i++) t += s_red[i];
        out[0] = t * scale;
    }
}

extern "C" void kernel_launch(void* const* d_in, const int* in_sizes, int n_in,
                              void* d_out, int out_size, void* d_ws, size_t ws_size,
                              hipStream_t stream) {
    const float* x    = (const float*)d_in[0];
    const float* y    = (const float*)d_in[1];
    const float* conf = (const float*)d_in[2];
    float* out = (float*)d_out;
    float* partials = (float*)d_ws;

    // Gaussian window, computed like the reference: float64 exp + normalize, cast f32
    GaussWin W;
    {
        double gd[11], s = 0.0;
        for (int i = 0; i < 11; i++) { gd[i] = exp(-((i - 5) * (i - 5)) / 4.5); s += gd[i]; }
        for (int i = 0; i < 11; i++) W.g[i] = (float)(gd[i] / s);
    }

    const int B = 16, C = 3;
    const float scale = 1.0f / (float)(B * C * IMG * IMG);
    const int gy_blocks = (IMG + TH - 1) / TH;              // 11 (last block masked)
    dim3 grid(IMG / TW, gy_blocks, B * C);                  // 16 x 11 x 48 = 8448 blocks
    const int nblocks = (IMG / TW) * gy_blocks * B * C;
    const int use_ws = (ws_size >= (size_t)nblocks * sizeof(float)) ? 1 : 0;

    if (!use_ws) {
        // fallback: atomic accumulation into d_out (poisoned before each call)
        hipMemsetAsync(d_out, 0, sizeof(float), stream);
    }
    ssim_tile_kernel<<<grid, 256, 0, stream>>>(x, y, conf, partials, out, use_ws, scale, W);
    if (use_ws) {
        reduce_kernel<<<1, 1024, 0, stream>>>(partials, nblocks, out, scale);
    }
}